// Round 4
// baseline (149.031 us; speedup 1.0000x reference)
//
#include <hip/hip_runtime.h>
#include <cstdint>

typedef unsigned short u16;
typedef __bf16 bf16x8 __attribute__((ext_vector_type(8)));
typedef float f32x4 __attribute__((ext_vector_type(4)));
typedef u16 u16x8 __attribute__((ext_vector_type(8)));

// Sizes fixed by reference: B=8, S=2048, I=256, H=256, M=1024
#define NX 4194304L   // key elems (16384*256)

__device__ __forceinline__ u16 f2bf(float f) {
  union { float f; uint32_t u; } v; v.f = f;
  uint32_t r = v.u + 0x7fffu + ((v.u >> 16) & 1u);
  return (u16)(r >> 16);
}

__device__ __forceinline__ u16x8 cvt8(float4 a, float4 b) {
  u16x8 o;
  o[0]=f2bf(a.x); o[1]=f2bf(a.y); o[2]=f2bf(a.z); o[3]=f2bf(a.w);
  o[4]=f2bf(b.x); o[5]=f2bf(b.y); o[6]=f2bf(b.z); o[7]=f2bf(b.w);
  return o;
}

// LDS layout for the 128x256 bf16 B-tile (exactly 64 KB):
//   addr_elems(row, k) = row*256 + (((k>>3) ^ (row&7)) << 3) + (k&7)
// 16B-chunk XOR swizzle keeps every wave64 b128 access at the LDS BW floor
// while staying 16B-aligned (ds_read_b128/ds_write_b128-safe).
__device__ __forceinline__ int sw_addr(int row, int k) {
  return row * 256 + ((((k >> 3) ^ (row & 7)) << 3)) + (k & 7);
}

// Barrier-free-K-loop NT GEMM: C[M,N] = op(A[M,K] * B[N,K]^T), K=256, fp32 in.
// B is staged ONCE to LDS with fused fp32->bf16 conversion (one barrier);
// the K-loop has no __syncthreads(), A-fragments load straight from global
// in MFMA fragment layout and are converted in-register, so the compiler can
// issue global loads arbitrarily early relative to the MFMAs.
// 128x128 tile, 256 threads (2x2 waves of 64x64), 16x16x32 bf16 MFMA.
// XCD_MAP: 1D grid decomposed as batch=bid&7 (pins each batch to one XCD,
// assuming round-robin block->XCD dispatch; worst case it's perf-neutral),
// bm fastest within an XCD (B-tile staged from HBM once, then L2-hot;
// per-XCD working set key_b 2.1MB + mem_b 1.05MB < 4MB L2).
template<bool RELU, bool XCD_MAP>
__global__ __launch_bounds__(256, 2)
void gemm_direct(const float* __restrict__ Ap, const float* __restrict__ Bp,
                 float* __restrict__ C, int N,
                 long sA_batch, long sB_batch, long sC_batch)
{
  constexpr int K = 256;
  __shared__ __align__(16) u16 sB[128 * 256];   // 64 KB

  int bm, bn, batch;
  if (XCD_MAP) {
    const int bid = blockIdx.x;      // 1024 blocks: 8 batch x 16 bm x 8 bn
    batch = bid & 7;                 // consecutive blocks -> different XCDs
    const int t = bid >> 3;          // XCD-local sequence
    bm = (t & 15) * 128;             // fastest: cycles M for a fixed B-tile
    bn = (t >> 4) * 128;
  } else {
    bn = blockIdx.x * 128; bm = blockIdx.y * 128; batch = 0;
  }

  const int tid  = threadIdx.x;
  const int wave = tid >> 6;
  const int lane = tid & 63;
  const int quad = lane >> 4;
  const int r    = lane & 15;
  const int wm   = wave >> 1;
  const int wn   = wave & 1;

  // ---- stage whole B tile (128 rows x K=256), fp32 -> bf16, once ----
  {
    const int rowS = tid >> 1;           // 0..127
    const int colS = (tid & 1) * 16;     // 0 or 16
    const float* Bg = Bp + (long)batch * sB_batch + (long)(bn + rowS) * K + colS;
    #pragma unroll
    for (int c = 0; c < 8; ++c) {
      const float* p = Bg + c * 32;
      float4 f0 = *(const float4*)(p);
      float4 f1 = *(const float4*)(p + 4);
      float4 f2 = *(const float4*)(p + 8);
      float4 f3 = *(const float4*)(p + 12);
      u16x8 lo = cvt8(f0, f1);
      u16x8 hi = cvt8(f2, f3);
      const int col = colS + c * 32;
      *(u16x8*)(sB + sw_addr(rowS, col))     = lo;
      *(u16x8*)(sB + sw_addr(rowS, col + 8)) = hi;
    }
  }
  __syncthreads();   // the only barrier in the kernel

  const float* Af = Ap + (long)batch * sA_batch + (long)(bm + wm * 64 + r) * K;

  f32x4 acc[4][4];
  #pragma unroll
  for (int i = 0; i < 4; i++)
    #pragma unroll
    for (int j = 0; j < 4; j++)
      acc[i][j] = f32x4{0.f, 0.f, 0.f, 0.f};

  #pragma unroll 2
  for (int kt = 0; kt < K; kt += 32) {
    bf16x8 af[4], bf[4];
    // A-fragments: A[m = lane&15][k = quad*8 + j], fp32 loaded + cvt in-reg
    #pragma unroll
    for (int i = 0; i < 4; ++i) {
      const float* p = Af + (long)i * 16 * K + kt + quad * 8;
      float4 a0 = *(const float4*)(p);
      float4 a1 = *(const float4*)(p + 4);
      u16x8 t = cvt8(a0, a1);
      af[i] = *(bf16x8*)&t;
    }
    // B-fragments from swizzled LDS: B^T[n = lane&15][k = quad*8 + j]
    #pragma unroll
    for (int j = 0; j < 4; ++j)
      bf[j] = *(const bf16x8*)(sB + sw_addr(wn * 64 + j * 16 + r, kt + quad * 8));
    #pragma unroll
    for (int i = 0; i < 4; ++i)
      #pragma unroll
      for (int j = 0; j < 4; ++j)
        acc[i][j] = __builtin_amdgcn_mfma_f32_16x16x32_bf16(af[i], bf[j], acc[i][j], 0, 0, 0);
  }

  // epilogue: C/D layout col=lane&15, row=quad*4+reg (verified m89/m91)
  float* Co = C + (long)batch * sC_batch;
  #pragma unroll
  for (int i = 0; i < 4; i++) {
    #pragma unroll
    for (int j = 0; j < 4; j++) {
      #pragma unroll
      for (int reg = 0; reg < 4; reg++) {
        const int row = bm + wm * 64 + i * 16 + quad * 4 + reg;
        const int col = bn + wn * 64 + j * 16 + r;
        float v = acc[i][j][reg];
        if (RELU) v = v > 0.f ? v : 0.f;
        Co[(long)row * N + col] = v;
      }
    }
  }
}

extern "C" void kernel_launch(void* const* d_in, const int* in_sizes, int n_in,
                              void* d_out, int out_size, void* d_ws, size_t ws_size,
                              hipStream_t stream) {
  const float* x   = (const float*)d_in[0];  // (8,2048,256) -> (16384,256)
  const float* mem = (const float*)d_in[1];  // (8,1024,256)
  const float* W   = (const float*)d_in[2];  // (256,256)
  float* out   = (float*)d_out;
  float* key_f = out;            // (16384,256) fp32
  float* val_f = out + NX;       // (8,2048,1024) fp32
  (void)d_ws; (void)ws_size;

  // 1) key = relu(x @ W^T): M=16384, N=256, K=256.
  //    A = x fp32 (direct frag loads + cvt), B = W fp32 (staged+cvt once).
  dim3 g1(2, 128, 1);
  gemm_direct<true, false><<<g1, 256, 0, stream>>>(
      x, W, key_f, 256, 0, 0, 0);

  // 2) val_b = key_b @ mem_b^T: per batch M=2048, N=1024, K=256.
  //    A = key fp32 straight from d_out (cvt in-reg), B = mem fp32 staged.
  //    1D grid, batch = bid&7 -> one batch per XCD, bm fastest.
  gemm_direct<false, true><<<dim3(1024, 1, 1), 256, 0, stream>>>(
      key_f, mem, val_f, 1024,
      (long)2048 * 256, (long)1024 * 256, (long)2048 * 1024);
}

// Round 5
// 129.188 us; speedup vs baseline: 1.1536x; 1.1536x over previous
//
#include <hip/hip_runtime.h>
#include <cstdint>

typedef unsigned short u16;
typedef __bf16 bf16x8 __attribute__((ext_vector_type(8)));
typedef float f32x4 __attribute__((ext_vector_type(4)));
typedef u16 u16x8 __attribute__((ext_vector_type(8)));

// Sizes fixed by reference: B=8, S=2048, I=256, H=256, M=1024
#define NX   4194304L   // key elems (16384*256)
#define NMEM 2097152L   // mem elems (8*1024*256)

__device__ __forceinline__ u16 f2bf(float f) {
  union { float f; uint32_t u; } v; v.f = f;
  uint32_t r = v.u + 0x7fffu + ((v.u >> 16) & 1u);
  return (u16)(r >> 16);
}

__device__ __forceinline__ u16x8 cvt8(float4 a, float4 b) {
  u16x8 o;
  o[0]=f2bf(a.x); o[1]=f2bf(a.y); o[2]=f2bf(a.z); o[3]=f2bf(a.w);
  o[4]=f2bf(b.x); o[5]=f2bf(b.y); o[6]=f2bf(b.z); o[7]=f2bf(b.w);
  return o;
}

// ---------------------------------------------------------------------------
// GEMM1: key = relu(x @ W^T), M=16384 N=256 K=256, fp32 inputs.
// m97 2-barrier global_load_lds K-loop, staging raw fp32 tiles (128x32 fp32 =
// 16 KB each). Swizzle: global_load_lds forces LDS slot = base + lane*16, but
// the GLOBAL address is per-lane, so logical 16B-chunk lc of row r is placed
// at LDS chunk lc ^ (r&7). Frag reads then hit 8 distinct 4-bank groups x 2
// lanes = 2-way aliasing = free (m136). fp32->bf16 conversion happens at
// frag-read time (cvt8), so no separate convert kernel for x/W.
// Tail: each of the 256 blocks also converts 8192 elems of mem -> bf16 in ws.
// ---------------------------------------------------------------------------
__global__ __launch_bounds__(256, 2)
void gemm1_kernel(const float* __restrict__ x, const float* __restrict__ W,
                  float* __restrict__ key_f, u16* __restrict__ key_bf,
                  const float* __restrict__ mem, u16* __restrict__ mem_bf)
{
  constexpr int K = 256;
  __shared__ __align__(16) float sA[128 * 32];   // 16 KB
  __shared__ __align__(16) float sB[128 * 32];   // 16 KB

  const int tid  = threadIdx.x;
  const int wave = tid >> 6;
  const int lane = tid & 63;
  const int quad = lane >> 4;
  const int r    = lane & 15;
  const int wm   = wave >> 1;
  const int wn   = wave & 1;
  const int bm   = blockIdx.y * 128;
  const int bn   = blockIdx.x * 128;

  const int o_base = wave * 1024 + lane * 16;   // this lane's LDS byte slot

  f32x4 acc[4][4];
  #pragma unroll
  for (int i = 0; i < 4; i++)
    #pragma unroll
    for (int j = 0; j < 4; j++)
      acc[i][j] = f32x4{0.f, 0.f, 0.f, 0.f};

  for (int kt = 0; kt < K; kt += 32) {
    __syncthreads();   // previous iteration's frag reads done
    #pragma unroll
    for (int rr = 0; rr < 4; rr++) {
      const int o   = rr * 4096 + o_base;
      const int row = o >> 7;            // 128 B per fp32 row (32 fp32)
      const int cp  = (o >> 4) & 7;      // LDS slot chunk within row
      const int c   = cp ^ (row & 7);    // global source chunk (XOR swizzle)
      const char* ga = (const char*)x + (long)(bm + row) * 1024 + kt * 4 + c * 16;
      const char* gb = (const char*)W + (long)(bn + row) * 1024 + kt * 4 + c * 16;
      char* la = (char*)sA + rr * 4096 + wave * 1024;
      char* lb = (char*)sB + rr * 4096 + wave * 1024;
      __builtin_amdgcn_global_load_lds((const __attribute__((address_space(1))) void*)ga,
                                       (__attribute__((address_space(3))) void*)la, 16, 0, 0);
      __builtin_amdgcn_global_load_lds((const __attribute__((address_space(1))) void*)gb,
                                       (__attribute__((address_space(3))) void*)lb, 16, 0, 0);
    }
    __syncthreads();   // compiler drains vmcnt(0) before barrier -> LDS valid

    // frags: logical chunk 2q / 2q+1 of row r sit at LDS chunks (2q)^s, (2q+1)^s
    bf16x8 af[4], bfr[4];
    const int s = r & 7;
    #pragma unroll
    for (int i = 0; i < 4; ++i) {
      const float* base = sA + (wm * 64 + i * 16 + r) * 32;
      float4 f0 = *(const float4*)(base + (((2 * quad)     ^ s) << 2));
      float4 f1 = *(const float4*)(base + (((2 * quad + 1) ^ s) << 2));
      u16x8 t = cvt8(f0, f1);
      af[i] = *(bf16x8*)&t;
    }
    #pragma unroll
    for (int j = 0; j < 4; ++j) {
      const float* base = sB + (wn * 64 + j * 16 + r) * 32;
      float4 f0 = *(const float4*)(base + (((2 * quad)     ^ s) << 2));
      float4 f1 = *(const float4*)(base + (((2 * quad + 1) ^ s) << 2));
      u16x8 t = cvt8(f0, f1);
      bfr[j] = *(bf16x8*)&t;
    }
    #pragma unroll
    for (int i = 0; i < 4; ++i)
      #pragma unroll
      for (int j = 0; j < 4; ++j)
        acc[i][j] = __builtin_amdgcn_mfma_f32_16x16x32_bf16(af[i], bfr[j], acc[i][j], 0, 0, 0);
  }

  // epilogue: C/D layout col=lane&15, row=quad*4+reg (verified m89/m91)
  #pragma unroll
  for (int i = 0; i < 4; i++) {
    #pragma unroll
    for (int j = 0; j < 4; j++) {
      #pragma unroll
      for (int reg = 0; reg < 4; reg++) {
        const int row = bm + wm * 64 + i * 16 + quad * 4 + reg;
        const int col = bn + wn * 64 + j * 16 + r;
        float v = acc[i][j][reg];
        v = v > 0.f ? v : 0.f;
        const long idx = (long)row * 256 + col;
        key_f[idx]  = v;
        key_bf[idx] = f2bf(v);
      }
    }
  }

  // fused mem -> bf16 convert: 256 blocks x 256 threads x 32 elems = NMEM
  {
    const int bid = blockIdx.y * 2 + blockIdx.x;     // 0..255
    const long e0 = ((long)bid * 256 + tid) * 32;
    #pragma unroll
    for (int c = 0; c < 4; ++c) {
      float4 f0 = *(const float4*)(mem + e0 + c * 8);
      float4 f1 = *(const float4*)(mem + e0 + c * 8 + 4);
      *(u16x8*)(mem_bf + e0 + c * 8) = cvt8(f0, f1);
    }
  }
}

// ---------------------------------------------------------------------------
// GEMM2: val_b = key_b @ mem_b^T, per batch M=2048 N=1024 K=256, bf16 in.
// Exact R1 m97 structure (measured-good): global_load_lds width-16 staging,
// 2-barrier K-loop, 128x128 tile, 4 waves, 16x16x32 bf16 MFMA.
// ---------------------------------------------------------------------------
__global__ __launch_bounds__(256, 2)
void gemm2_kernel(const u16* __restrict__ A, const u16* __restrict__ B,
                  float* __restrict__ C)
{
  constexpr int K = 256;
  __shared__ __align__(16) u16 sA[128 * 32];   // 8 KB
  __shared__ __align__(16) u16 sB[128 * 32];   // 8 KB
  const int tid  = threadIdx.x;
  const int wave = tid >> 6;
  const int lane = tid & 63;
  const int quad = lane >> 4;
  const int r    = lane & 15;
  const int wm   = wave >> 1;
  const int wn   = wave & 1;
  const int bm   = blockIdx.y * 128;
  const int bn   = blockIdx.x * 128;
  const int batch = blockIdx.z;

  const char* Ab = (const char*)(A + (long)batch * 2048 * 256);
  const char* Bb = (const char*)(B + (long)batch * 1024 * 256);
  const long ldr = 512;   // K*2 bytes per row

  f32x4 acc[4][4];
  #pragma unroll
  for (int i = 0; i < 4; i++)
    #pragma unroll
    for (int j = 0; j < 4; j++)
      acc[i][j] = f32x4{0.f, 0.f, 0.f, 0.f};

  const int o0 = wave * 1024 + lane * 16;

  for (int kt = 0; kt < K; kt += 32) {
    __syncthreads();
    #pragma unroll
    for (int rr = 0; rr < 2; rr++) {
      const int o    = rr * 4096 + o0;
      const int row  = o >> 6;     // 64 B per bf16 row (32 bf16)
      const int colb = o & 63;
      const char* ga = Ab + (long)(bm + row) * ldr + (long)kt * 2 + colb;
      const char* gb = Bb + (long)(bn + row) * ldr + (long)kt * 2 + colb;
      char* la = (char*)sA + rr * 4096 + wave * 1024;
      char* lb = (char*)sB + rr * 4096 + wave * 1024;
      __builtin_amdgcn_global_load_lds((const __attribute__((address_space(1))) void*)ga,
                                       (__attribute__((address_space(3))) void*)la, 16, 0, 0);
      __builtin_amdgcn_global_load_lds((const __attribute__((address_space(1))) void*)gb,
                                       (__attribute__((address_space(3))) void*)lb, 16, 0, 0);
    }
    __syncthreads();

    bf16x8 af[4], bf[4];
    #pragma unroll
    for (int i = 0; i < 4; i++)
      af[i] = *(const bf16x8*)(sA + (wm * 64 + i * 16 + r) * 32 + quad * 8);
    #pragma unroll
    for (int j = 0; j < 4; j++)
      bf[j] = *(const bf16x8*)(sB + (wn * 64 + j * 16 + r) * 32 + quad * 8);
    #pragma unroll
    for (int i = 0; i < 4; i++)
      #pragma unroll
      for (int j = 0; j < 4; j++)
        acc[i][j] = __builtin_amdgcn_mfma_f32_16x16x32_bf16(af[i], bf[j], acc[i][j], 0, 0, 0);
  }

  float* Co = C + (long)batch * 2048 * 1024;
  #pragma unroll
  for (int i = 0; i < 4; i++) {
    #pragma unroll
    for (int j = 0; j < 4; j++) {
      #pragma unroll
      for (int reg = 0; reg < 4; reg++) {
        const int row = bm + wm * 64 + i * 16 + quad * 4 + reg;
        const int col = bn + wn * 64 + j * 16 + r;
        Co[(long)row * 1024 + col] = acc[i][j][reg];
      }
    }
  }
}

extern "C" void kernel_launch(void* const* d_in, const int* in_sizes, int n_in,
                              void* d_out, int out_size, void* d_ws, size_t ws_size,
                              hipStream_t stream) {
  const float* x   = (const float*)d_in[0];  // (8,2048,256) -> (16384,256)
  const float* mem = (const float*)d_in[1];  // (8,1024,256)
  const float* W   = (const float*)d_in[2];  // (256,256)
  float* out   = (float*)d_out;
  float* key_f = out;            // (16384,256) fp32
  float* val_f = out + NX;       // (8,2048,1024) fp32
  u16* key_bf  = (u16*)d_ws;         // 8.4 MB
  u16* mem_bf  = (u16*)d_ws + NX;    // 4.2 MB

  // 1) key = relu(x @ W^T), fp32 staged via swizzled global_load_lds,
  //    dual-store fp32+bf16, fused mem->bf16 convert.
  dim3 g1(2, 128, 1);
  gemm1_kernel<<<g1, 256, 0, stream>>>(x, W, key_f, key_bf, mem, mem_bf);

  // 2) val_b = key_b @ mem_b^T, pure-bf16 m97 structure (R1-verbatim).
  dim3 g2(8, 16, 8);
  gemm2_kernel<<<g2, 256, 0, stream>>>(key_bf, mem_bf, val_f);
}